// Round 9
// baseline (137.764 us; speedup 1.0000x reference)
//
#include <hip/hip_runtime.h>
#include <cstdint>
#include <cstddef>
#include <math.h>

typedef unsigned long long u64;
typedef unsigned int u32;

#define BB 4
#define NN 32768
#define DD 512
#define KK 8192
#define NBIN 2048
#define RPW 8        // score: rows per wave
#define RPG 4        // gather: rows per wave

// ws layout (bytes):
//   0x000000: keys   [4][32768] u64   (1 MiB)
//   0x100000: below  [4][8192]  u64   (256 KiB)  bins < B*
//   0x140000: scr    [4][8192]  u64   (256 KiB)  bin == B*
//   0x200000: hist   [4][2048]  u32
//   0x208000: base   [4][2048]  u32
//   0x210000: curs   [4][2048]  u32
//   0x218000: meta   [4][4]     u32   {m, cntB, Bstar, pad}
#define BELOW_OFF 0x100000
#define SCR_OFF   0x140000
#define HIST_OFF  0x200000
#define ZERO_BYTES (3 * 4 * NBIN * 4 + 64)

// ---------------- score kernel: RPW rows per wave (verified R6) ----------------
__global__ __launch_bounds__(256) void score_kernel(const float* __restrict__ h,
                                                    const float* __restrict__ sf,
                                                    u64* __restrict__ keys) {
    int wave = (blockIdx.x * 256 + threadIdx.x) >> 6;
    int lane = threadIdx.x & 63;
    int b  = wave >> 12;
    int n0 = (wave & 4095) * RPW;
    const float4* s4 = (const float4*)(sf) + (size_t)b * 128;
    float4 w0 = s4[lane], w1 = s4[lane + 64];
    const float4* hb = (const float4*)(h) + ((size_t)b * NN + n0) * 128;
    float4 r0[RPW], r1[RPW];
#pragma unroll
    for (int r = 0; r < RPW; ++r) {
        r0[r] = hb[r * 128 + lane];
        r1[r] = hb[r * 128 + 64 + lane];
    }
    u64 mykey = 0;
#pragma unroll
    for (int r = 0; r < RPW; ++r) {
        double acc = (double)r0[r].x * w0.x + (double)r0[r].y * w0.y +
                     (double)r0[r].z * w0.z + (double)r0[r].w * w0.w +
                     (double)r1[r].x * w1.x + (double)r1[r].y * w1.y +
                     (double)r1[r].z * w1.z + (double)r1[r].w * w1.w;
#pragma unroll
        for (int off = 32; off >= 1; off >>= 1)
            acc += __shfl_xor(acc, off, 64);
        // f32 sigmoid pipeline — replicates reference tie-buckets near
        // saturation (validated round 2; do not change).
        float x = (float)acc;
        float e = expf(-x);
        float s = 1.0f / (1.0f + e);
        u64 key = ((u64)(~__float_as_uint(s)) << 32) | (unsigned)(n0 + r);
        if (lane == r) mykey = key;
    }
    if (lane < RPW)
        keys[((size_t)b << 15) + n0 + lane] = mykey;
}

// ---------------- histogram of top 11 key bits ----------------
__global__ __launch_bounds__(256) void hist_kernel(const u64* __restrict__ keys,
                                                   u32* __restrict__ hist) {
    __shared__ u32 hloc[NBIN];
    for (int i = threadIdx.x; i < NBIN; i += 256) hloc[i] = 0;
    __syncthreads();
    int b  = blockIdx.x >> 6;            // 64 blocks per batch
    int e0 = (blockIdx.x & 63) * 512;
    const u64* kb = keys + ((size_t)b << 15);
#pragma unroll
    for (int q = 0; q < 2; ++q) {
        u64 k = kb[e0 + threadIdx.x + q * 256];
        atomicAdd(&hloc[(u32)(k >> 53)], 1u);
    }
    __syncthreads();
    for (int i = threadIdx.x; i < NBIN; i += 256)
        if (hloc[i]) atomicAdd(&hist[b * NBIN + i], hloc[i]);
}

// ---------------- scan bins, find threshold bin B*, write bases + meta ----------------
__global__ __launch_bounds__(256) void plan_kernel(const u32* __restrict__ hist,
                                                   u32* __restrict__ base,
                                                   u32* __restrict__ meta) {
    __shared__ u32 partial[256];
    int b = blockIdx.x, t = threadIdx.x;
    const u32* hb = hist + b * NBIN;
    u32 loc[8], s = 0;
#pragma unroll
    for (int q = 0; q < 8; ++q) { loc[q] = hb[t * 8 + q]; s += loc[q]; }
    partial[t] = s;
    __syncthreads();
    for (int off = 1; off < 256; off <<= 1) {
        u32 add = (t >= off) ? partial[t - off] : 0;
        __syncthreads();
        partial[t] += add;
        __syncthreads();
    }
    u32 pre = partial[t] - s;            // exclusive prefix of this thread's 8 bins
#pragma unroll
    for (int q = 0; q < 8; ++q) {
        int bin = t * 8 + q;
        base[b * NBIN + bin] = pre;
        if (pre <= (u32)(KK - 1) && pre + loc[q] > (u32)(KK - 1)) {
            meta[b * 4 + 0] = pre;       // m: count strictly below B*
            meta[b * 4 + 1] = loc[q];    // cntB
            meta[b * 4 + 2] = (u32)bin;  // B*
        }
        pre += loc[q];
    }
}

// ---------------- scatter: bins < B* -> below (bin-segmented), == B* -> scratch ----------------
// Unordered within bins (atomics); the subsequent full-u64 sort canonicalizes.
__global__ __launch_bounds__(256) void scatter_kernel(const u64* __restrict__ keys,
                                                      const u32* __restrict__ base,
                                                      u32* __restrict__ curs,
                                                      const u32* __restrict__ meta,
                                                      u64* __restrict__ below,
                                                      u64* __restrict__ scr) {
    __shared__ u32 cnt[NBIN];
    __shared__ u32 bb[NBIN];
    for (int i = threadIdx.x; i < NBIN; i += 256) cnt[i] = 0;
    __syncthreads();
    int b  = blockIdx.x >> 6;
    int e0 = (blockIdx.x & 63) * 512;
    u32 Bs = meta[b * 4 + 2];
    const u64* kb = keys + ((size_t)b << 15);
    u64 k0 = kb[e0 + threadIdx.x];
    u64 k1 = kb[e0 + threadIdx.x + 256];
    u32 b0 = (u32)(k0 >> 53), b1 = (u32)(k1 >> 53);
    if (b0 <= Bs) atomicAdd(&cnt[b0], 1u);
    if (b1 <= Bs) atomicAdd(&cnt[b1], 1u);
    __syncthreads();
    for (int i = threadIdx.x; i < NBIN; i += 256) {
        u32 c = cnt[i];
        bb[i] = c ? atomicAdd(&curs[b * NBIN + i], c) : 0;
        cnt[i] = 0;
    }
    __syncthreads();
    if (b0 <= Bs) {
        u32 pos = bb[b0] + atomicAdd(&cnt[b0], 1u);
        if (b0 < Bs) below[((size_t)b << 13) + base[b * NBIN + b0] + pos] = k0;
        else if (pos < KK) scr[((size_t)b << 13) + pos] = k0;
    }
    if (b1 <= Bs) {
        u32 pos = bb[b1] + atomicAdd(&cnt[b1], 1u);
        if (b1 < Bs) below[((size_t)b << 13) + base[b * NBIN + b1] + pos] = k1;
        else if (pos < KK) scr[((size_t)b << 13) + pos] = k1;
    }
}

// ---------------- bitonic primitives (verified R6/R8) ----------------
template<int J>
__device__ __forceinline__ void reg_ce(u64 v[8], int bse, int stage) {
#pragma unroll
    for (int e = 0; e < 8; ++e) {
        if ((e & J) == 0) {
            const int f = e | J;
            bool up = (((bse + e) & stage) == 0);
            u64 a = v[e], b = v[f];
            bool sw = up ? (a > b) : (a < b);
            if (sw) { v[e] = b; v[f] = a; }
        }
    }
}

__device__ __forceinline__ void reg_tail(u64 v[8], int bse, int stage, int jmax) {
    if (jmax >= 4) reg_ce<4>(v, bse, stage);
    if (jmax >= 2) reg_ce<2>(v, bse, stage);
    reg_ce<1>(v, bse, stage);
}

__device__ __forceinline__ void shfl_pass(u64 v[8], int t, int bse, int stage, int j) {
    int m = j >> 3;
    bool lower = ((t & m) == 0);
#pragma unroll
    for (int e = 0; e < 8; ++e) {
        u64 pv = __shfl_xor(v[e], m, 64);
        bool up = (((bse + e) & stage) == 0);
        bool tm = (lower == up);
        bool lt = v[e] < pv;
        v[e] = (tm == lt) ? v[e] : pv;
    }
}

__device__ __forceinline__ void lds_pass(u64 v[8], unsigned* lo, unsigned* hi,
                                         int t, int bse, int stage, int j) {
    __syncthreads();
#pragma unroll
    for (int e = 0; e < 8; ++e) {
        lo[e * 1024 + t] = (unsigned)v[e];
        hi[e * 1024 + t] = (unsigned)(v[e] >> 32);
    }
    __syncthreads();
    int pt = t ^ (j >> 3);
    bool lower = ((t & (j >> 3)) == 0);
#pragma unroll
    for (int e = 0; e < 8; ++e) {
        u64 pv = ((u64)hi[e * 1024 + pt] << 32) | (u64)lo[e * 1024 + pt];
        bool up = (((bse + e) & stage) == 0);
        bool tm = (lower == up);
        bool lt = v[e] < pv;
        v[e] = (tm == lt) ? v[e] : pv;
    }
}

// ---------------- sentinel-padded 8192 bitonic sort: below (blk 0-3) & scratch (blk 4-7) ----------------
__global__ __launch_bounds__(1024) void sort8k_kernel(u64* __restrict__ below,
                                                      u64* __restrict__ scr,
                                                      const u32* __restrict__ meta) {
    __shared__ unsigned lo[8192];
    __shared__ unsigned hi[8192];
    int b = blockIdx.x & 3, which = blockIdx.x >> 2;
    u64* buf = (which ? scr : below) + ((size_t)b << 13);
    u32 cnt = meta[b * 4 + which];       // which=0 -> m, 1 -> cntB
    int t = threadIdx.x, bse = t * 8;
    u64 v[8];
#pragma unroll
    for (int e = 0; e < 8; ++e) {
        int i = bse + e;
        v[e] = (i < (int)cnt) ? buf[i] : ~0ULL;   // sentinel: sorts past all real keys
    }
    for (int stage = 2; stage <= 8192; stage <<= 1) {
        int j = stage >> 1;
        for (; j >= 512; j >>= 1) lds_pass(v, lo, hi, t, bse, stage, j);
        for (; j >= 8; j >>= 1)   shfl_pass(v, t, bse, stage, j);
        reg_tail(v, bse, stage, (stage >> 1) < 4 ? (stage >> 1) : 4);
    }
#pragma unroll
    for (int q = 0; q < 4; ++q) {
        ulonglong2 p; p.x = v[2 * q]; p.y = v[2 * q + 1];
        ((ulonglong2*)(buf + bse))[q] = p;
    }
}

// ---------------- gather + scale: RPG rows per wave (verified R6; two-region keys) ----------------
__global__ __launch_bounds__(256) void gather_kernel(const float* __restrict__ h,
                                                     const u64* __restrict__ below,
                                                     const u64* __restrict__ scr,
                                                     const u32* __restrict__ meta,
                                                     float* __restrict__ out) {
    int wave = (blockIdx.x * 256 + threadIdx.x) >> 6;
    int lane = threadIdx.x & 63;
    int b  = wave >> 11;
    int j0 = (wave & 2047) * RPG;
    u32 m = meta[b * 4];
    u64 k[RPG];
#pragma unroll
    for (int r = 0; r < RPG; ++r) {
        int j = j0 + r;
        k[r] = (j < (int)m) ? below[((size_t)b << 13) + j]
                            : scr[((size_t)b << 13) + (j - m)];
    }
    float4 x0[RPG], x1[RPG];
    const float4* srcp[RPG];
#pragma unroll
    for (int r = 0; r < RPG; ++r) {
        int idx = (int)(unsigned)(k[r] & 0xFFFFFFFFu);
        srcp[r] = (const float4*)(h) + ((size_t)b * NN + idx) * 128;
        x0[r] = srcp[r][lane];
        x1[r] = srcp[r][lane + 64];
    }
#pragma unroll
    for (int r = 0; r < RPG; ++r) {
        float v = __uint_as_float(~(unsigned)(k[r] >> 32));
        float4* dst = (float4*)(out) + ((size_t)b * KK + j0 + r) * 128;
        float4 a = x0[r], c = x1[r];
        a.x *= v; a.y *= v; a.z *= v; a.w *= v;
        c.x *= v; c.y *= v; c.z *= v; c.w *= v;
        dst[lane] = a;
        dst[lane + 64] = c;
    }
}

extern "C" void kernel_launch(void* const* d_in, const int* in_sizes, int n_in,
                              void* d_out, int out_size, void* d_ws, size_t ws_size,
                              hipStream_t stream) {
    const float* h  = (const float*)d_in[0];
    const float* sf = (const float*)d_in[1];
    float* out = (float*)d_out;
    u64* keys  = (u64*)d_ws;
    u64* below = (u64*)((char*)d_ws + BELOW_OFF);
    u64* scr   = (u64*)((char*)d_ws + SCR_OFF);
    u32* hist  = (u32*)((char*)d_ws + HIST_OFF);
    u32* base  = hist + BB * NBIN;
    u32* curs  = base + BB * NBIN;
    u32* meta  = curs + BB * NBIN;

    hipMemsetAsync((void*)hist, 0, ZERO_BYTES, stream);  // hist+base+curs+meta
    score_kernel<<<4096, 256, 0, stream>>>(h, sf, keys);
    hist_kernel<<<256, 256, 0, stream>>>(keys, hist);
    plan_kernel<<<BB, 256, 0, stream>>>(hist, base, meta);
    scatter_kernel<<<256, 256, 0, stream>>>(keys, base, curs, meta, below, scr);
    sort8k_kernel<<<8, 1024, 0, stream>>>(below, scr, meta);
    gather_kernel<<<2048, 256, 0, stream>>>(h, below, scr, meta, out);
}